// Round 6
// baseline (1077.715 us; speedup 1.0000x reference)
//
#include <hip/hip_runtime.h>
#include <hip/hip_bf16.h>

// ISTA split-bf16 MFMA, round 6 = round 5 + 2 blocks/CU latency hiding.
// C' = S · d^T (A = S register-resident, B = d from LDS). d packed
// u32 = bf16_hi | bf16_lo<<16, [row][k], XOR-swizzled byte ^= (row&7)<<4.
//
// R6 changes vs R5 (perf only — per-row arithmetic identical, so numerics
// are bitwise R5's, absmax 0.03125):
//  - ROWS 16 -> 8, grid 256 -> 512 = 2 independent blocks/CU: one block's
//    MFMA-chain/LDS/barrier stalls hide under the other's issue (m114).
//    R5 ran 1 wave/SIMD (Occupancy 11.7%) with ~1675 cy/iter vs ~600 cy of
//    work -- pure exposed latency.
//  - B-operand lanes l15>=8 read row l15&7 (same address as partner lane ->
//    LDS broadcast). This kills the measured 3.277e7 bank-conflict cycles
//    (2-way chunk alias l15 vs l15+8 on every b128 read in R3/R5); MFMA
//    output columns are independent, so the duplicated B columns only feed
//    discarded outputs.
//  - Epilogue writes / Wy / output masked to l15<8 (also avoids OOB y reads).

#define ROWS     8
#define KPAD     128
#define N_DIM    100
#define M_DIM    70
#define NTHREADS 256

typedef __attribute__((ext_vector_type(8))) short short8;
typedef __attribute__((ext_vector_type(4))) float f32x4;
typedef __attribute__((ext_vector_type(4))) unsigned int u32x4;

static __device__ __forceinline__ unsigned short f2bf(float f) {
    unsigned u = __float_as_uint(f);
    u += 0x7FFF + ((u >> 16) & 1);          // RNE
    return (unsigned short)(u >> 16);
}
static __device__ __forceinline__ float bf2f(unsigned short b) {
    return __uint_as_float(((unsigned)b) << 16);
}

union v16 { u32x4 u; short8 s; };

__global__ __launch_bounds__(NTHREADS)
void ista_mfma4(const float* __restrict__ y,
                const float* __restrict__ S,
                const float* __restrict__ W,
                const float* __restrict__ thr,
                const int*   __restrict__ numIter,
                float* __restrict__ out)
{
    __shared__ __align__(16) unsigned int dp[2][ROWS * KPAD];  // packed hi|lo

    const int t    = threadIdx.x;
    const int wv   = t >> 6;        // wave 0..3 (2 N-tiles each)
    const int l    = t & 63;
    const int l15  = l & 15;
    const int lr   = l15 & 7;       // d-row this lane touches (broadcast pair)
    const int lg   = l >> 4;
    const int row0 = blockIdx.x * ROWS;
    const float th  = thr[0];
    const int iters = numIter[0];
    const bool rlane = (l15 < 8);   // lane owns a real d-row
    const unsigned swz = (unsigned)(lr << 4);

    // ---- one-time: S fragments as MFMA *A* operand (row = l15 = j-in-tile) ----
    // All 16 l15 lanes valid here: A rows are output columns j, not d-rows.
    short8 Sh[2][4], Sl[2][4];
    #pragma unroll
    for (int n2 = 0; n2 < 2; ++n2) {
        const int jg = (wv * 2 + n2) * 16 + l15;           // global output column
        #pragma unroll
        for (int kt = 0; kt < 4; ++kt) {
            #pragma unroll
            for (int i = 0; i < 8; ++i) {
                const int k = kt * 32 + lg * 8 + i;
                const float v = (jg < N_DIM && k < N_DIM) ? S[jg * N_DIM + k] : 0.f;
                const unsigned short hb = f2bf(v);
                Sh[n2][kt][i] = (short)hb;
                Sl[n2][kt][i] = (short)f2bf(v - bf2f(hb));
            }
        }
    }

    // ---- one-time: Wy in C' layout (lane: d-row = lr, j = tile + lg*4+q) ----
    f32x4 Wyr[2];
    #pragma unroll
    for (int n2 = 0; n2 < 2; ++n2) {
        #pragma unroll
        for (int q = 0; q < 4; ++q) {
            const int j = (wv * 2 + n2) * 16 + lg * 4 + q;
            float acc = 0.f;
            if (j < N_DIM) {
                const float* yr = y + (size_t)(row0 + lr) * M_DIM;
                const float* wr = W + (size_t)j * M_DIM;
                #pragma unroll 10
                for (int m = 0; m < M_DIM; ++m) acc = fmaf(yr[m], wr[m], acc);
            }
            Wyr[n2][q] = acc;
        }
    }

    // ---- zero buffer 0 ----
    for (int idx = t; idx < ROWS * KPAD; idx += NTHREADS) dp[0][idx] = 0u;
    __syncthreads();

    const unsigned* rb = dp[0];
    unsigned*       wb = dp[1];

    for (int it = 0; it < iters; ++it) {
        // ---- load + unpack d fragments (B col = d-row; l15>=8 broadcasts lr) ----
        short8 Bh[4], Bl[4];
        #pragma unroll
        for (int kt = 0; kt < 4; ++kt) {
            const unsigned base = (unsigned)((lr * KPAD + kt * 32 + lg * 8) * 4);
            const u32x4 pa = *(const u32x4*)((const char*)rb + ((base      ) ^ swz));
            const u32x4 pb = *(const u32x4*)((const char*)rb + ((base + 16u) ^ swz));
            v16 h, lo;
            h.u[0]  = __builtin_amdgcn_perm(pa[1], pa[0], 0x05040100u);
            h.u[1]  = __builtin_amdgcn_perm(pa[3], pa[2], 0x05040100u);
            h.u[2]  = __builtin_amdgcn_perm(pb[1], pb[0], 0x05040100u);
            h.u[3]  = __builtin_amdgcn_perm(pb[3], pb[2], 0x05040100u);
            lo.u[0] = __builtin_amdgcn_perm(pa[1], pa[0], 0x07060302u);
            lo.u[1] = __builtin_amdgcn_perm(pa[3], pa[2], 0x07060302u);
            lo.u[2] = __builtin_amdgcn_perm(pb[1], pb[0], 0x07060302u);
            lo.u[3] = __builtin_amdgcn_perm(pb[3], pb[2], 0x07060302u);
            Bh[kt] = h.s;
            Bl[kt] = lo.s;
        }

        // ---- 24 MFMAs, 3 independent chains per N-tile (dep depth = 4) ----
        f32x4 Chh[2] = { Wyr[0], Wyr[1] };
        f32x4 Chl[2] = { {0,0,0,0}, {0,0,0,0} };
        f32x4 Clh[2] = { {0,0,0,0}, {0,0,0,0} };
        #pragma unroll
        for (int kt = 0; kt < 4; ++kt) {
            #pragma unroll
            for (int n2 = 0; n2 < 2; ++n2)
                Chh[n2] = __builtin_amdgcn_mfma_f32_16x16x32_bf16(Sh[n2][kt], Bh[kt], Chh[n2], 0, 0, 0);
            #pragma unroll
            for (int n2 = 0; n2 < 2; ++n2)
                Chl[n2] = __builtin_amdgcn_mfma_f32_16x16x32_bf16(Sh[n2][kt], Bl[kt], Chl[n2], 0, 0, 0);
            #pragma unroll
            for (int n2 = 0; n2 < 2; ++n2)
                Clh[n2] = __builtin_amdgcn_mfma_f32_16x16x32_bf16(Sl[n2][kt], Bh[kt], Clh[n2], 0, 0, 0);
        }

        // ---- epilogue: sum chains, softthr, pack, b128 write (real rows only) ----
        #pragma unroll
        for (int n2 = 0; n2 < 2; ++n2) {
            u32x4 pk;
            #pragma unroll
            for (int q = 0; q < 4; ++q) {
                const float s = Chh[n2][q] + Chl[n2][q] + Clh[n2][q];
                float mag = fabsf(s) - th;
                mag = mag > 0.f ? mag : 0.f;
                const float r = (s >= 0.f) ? mag : -mag;
                const unsigned short hb = f2bf(r);
                const unsigned short lb = f2bf(r - bf2f(hb));
                pk[q] = (unsigned)hb | ((unsigned)lb << 16);
            }
            if (rlane) {
                const unsigned boff =
                    (unsigned)((lr * KPAD + (wv * 2 + n2) * 16 + lg * 4) * 4) ^ swz;
                *(u32x4*)((char*)wb + boff) = pk;
            }
        }

        __syncthreads();          // single barrier: next iter reads what we wrote
        const unsigned* tmp = rb; rb = wb; wb = (unsigned*)tmp;
    }

    // ---- output: unpack hi+lo, write global ----
    for (int idx = t; idx < ROWS * N_DIM; idx += NTHREADS) {
        const int r = idx / N_DIM;
        const int j = idx - r * N_DIM;
        const unsigned off = (unsigned)((r * KPAD + j) * 4) ^ (unsigned)((r & 7) << 4);
        const unsigned v = *(const unsigned*)((const char*)rb + off);
        out[(size_t)(row0 + r) * N_DIM + j] =
            bf2f((unsigned short)(v & 0xFFFFu)) + bf2f((unsigned short)(v >> 16));
    }
}

extern "C" void kernel_launch(void* const* d_in, const int* in_sizes, int n_in,
                              void* d_out, int out_size, void* d_ws, size_t ws_size,
                              hipStream_t stream) {
    const float* y       = (const float*)d_in[0];
    const float* S       = (const float*)d_in[1];
    const float* W       = (const float*)d_in[2];
    const float* thr     = (const float*)d_in[3];
    const int*   numIter = (const int*)d_in[4];
    float* out = (float*)d_out;

    const int Brows = in_sizes[0] / M_DIM;   // 4096
    const int nblk  = Brows / ROWS;          // 512 blocks = 2/CU
    ista_mfma4<<<nblk, NTHREADS, 0, stream>>>(y, S, W, thr, numIter, out);
}

// Round 7
// 530.362 us; speedup vs baseline: 2.0320x; 2.0320x over previous
//
#include <hip/hip_runtime.h>
#include <hip/hip_bf16.h>

// ISTA split-bf16 MFMA, round 7: R5 structure, VALU-lean inner loop.
// C' = S · d^T (A = S register-resident, B = d from LDS, m89 C-layout:
// m=lg*4+q -> output col j, n=l15 -> d-row). ROWS=16, grid=256 (1 block/CU,
// 4 waves, 2 N-tiles/wave) -- R6 proved half-filled tiles at 2 blocks/CU
// duplicate work and regress.
//
// R7 changes (VALU instruction count was the limiter: VALUBusy*dur ~ 580-850
// cy/SIMD-iter vs ~120 MFMA):
//  - dh/dl SEPARATE u16 arrays (R3 layout): b128 read = short8 fragment
//    directly, no v_perm unpack (R5's perms made it slower than R3).
//  - softthr via v_med3_f32: x - med3(x,-th,th), 2 instrs, bit-identical.
//  - v_cvt_pk_bf16_f32 (inline asm, RNE == manual f2bf) for hi and lo
//    splits; packed u32 pairs are exactly the ds_write_b64 payloads.
// Numerics: same product set (Sh*Bh + Sh*Bl + Sl*Bh, 4 kt, Wy seed), same
// RNE -> absmax stays 0.03125.
// Bank note: b128 over 16 distinct rows is structurally >=2-phase (256B of
// chunks vs 128B bank window) -> the constant 3.3e7 conflict counter is
// unfixable and costs only ~4cy/read.

#define ROWS     16
#define KPAD     128
#define N_DIM    100
#define M_DIM    70
#define NTHREADS 256

typedef __attribute__((ext_vector_type(8))) short short8;
typedef __attribute__((ext_vector_type(4))) float f32x4;

static __device__ __forceinline__ unsigned short f2bf(float f) {
    unsigned u = __float_as_uint(f);
    u += 0x7FFF + ((u >> 16) & 1);          // RNE
    return (unsigned short)(u >> 16);
}
static __device__ __forceinline__ float bf2f(unsigned short b) {
    return __uint_as_float(((unsigned)b) << 16);
}
// packed RNE: low16 = bf16(a), high16 = bf16(b)
static __device__ __forceinline__ unsigned cvt_pk_bf16(float a, float b) {
    unsigned r;
    asm("v_cvt_pk_bf16_f32 %0, %1, %2" : "=v"(r) : "v"(a), "v"(b));
    return r;
}
static __device__ __forceinline__ float med3f(float x, float lo, float hi) {
    float r;
    asm("v_med3_f32 %0, %1, %2, %3" : "=v"(r) : "v"(x), "v"(lo), "v"(hi));
    return r;
}

__global__ __launch_bounds__(NTHREADS)
void ista_mfma5(const float* __restrict__ y,
                const float* __restrict__ S,
                const float* __restrict__ W,
                const float* __restrict__ thr,
                const int*   __restrict__ numIter,
                float* __restrict__ out)
{
    __shared__ __align__(16) unsigned short dh[2][ROWS * KPAD];  // d hi bf16 bits
    __shared__ __align__(16) unsigned short dl[2][ROWS * KPAD];  // d lo bf16 bits

    const int t    = threadIdx.x;
    const int wv   = t >> 6;        // wave 0..3 (2 N-tiles each)
    const int l    = t & 63;
    const int l15  = l & 15;
    const int lg   = l >> 4;
    const int row0 = blockIdx.x * ROWS;
    const float th  = thr[0];
    const float nth = -th;
    const int iters = numIter[0];
    const unsigned swz = (unsigned)((l15 & 7) << 4);

    // ---- one-time: S fragments as MFMA *A* operand (row = l15 = j-in-tile) ----
    short8 Sh[2][4], Sl[2][4];
    #pragma unroll
    for (int n2 = 0; n2 < 2; ++n2) {
        const int jg = (wv * 2 + n2) * 16 + l15;           // global output column
        #pragma unroll
        for (int kt = 0; kt < 4; ++kt) {
            #pragma unroll
            for (int i = 0; i < 8; ++i) {
                const int k = kt * 32 + lg * 8 + i;
                const float v = (jg < N_DIM && k < N_DIM) ? S[jg * N_DIM + k] : 0.f;
                const unsigned short hb = f2bf(v);
                Sh[n2][kt][i] = (short)hb;
                Sl[n2][kt][i] = (short)f2bf(v - bf2f(hb));
            }
        }
    }

    // ---- one-time: Wy in C' layout (lane: d-row = l15, j = tile + lg*4+q) ----
    f32x4 Wyr[2];
    #pragma unroll
    for (int n2 = 0; n2 < 2; ++n2) {
        #pragma unroll
        for (int q = 0; q < 4; ++q) {
            const int j = wv * 32 + n2 * 16 + lg * 4 + q;
            float acc = 0.f;
            if (j < N_DIM) {
                const float* yr = y + (size_t)(row0 + l15) * M_DIM;
                const float* wr = W + (size_t)j * M_DIM;
                #pragma unroll 10
                for (int m = 0; m < M_DIM; ++m) acc = fmaf(yr[m], wr[m], acc);
            }
            Wyr[n2][q] = acc;
        }
    }

    // ---- zero buffer 0 ----
    for (int idx = t; idx < ROWS * KPAD; idx += NTHREADS) {
        dh[0][idx] = 0; dl[0][idx] = 0;
    }
    __syncthreads();

    // loop-invariant byte offsets (XOR swizzle on byte bits 4..6)
    unsigned roff[4];
    #pragma unroll
    for (int kt = 0; kt < 4; ++kt)
        roff[kt] = ((unsigned)(l15 * 256 + kt * 64 + lg * 16)) ^ swz;
    unsigned woff[2];
    #pragma unroll
    for (int n2 = 0; n2 < 2; ++n2)
        woff[n2] = ((unsigned)(l15 * 256 + wv * 64 + n2 * 32 + lg * 8)) ^ swz;

    int cur = 0;
    for (int it = 0; it < iters; ++it) {
        const char* rh = (const char*)dh[cur];
        const char* rl = (const char*)dl[cur];
        char* wh = (char*)dh[cur ^ 1];
        char* wl = (char*)dl[cur ^ 1];

        // ---- 8 b128 reads: fragments directly, no unpack ----
        short8 Bh[4], Bl[4];
        #pragma unroll
        for (int kt = 0; kt < 4; ++kt) {
            Bh[kt] = *(const short8*)(rh + roff[kt]);
            Bl[kt] = *(const short8*)(rl + roff[kt]);
        }

        // ---- 24 MFMAs, 3 independent chains per N-tile (dep depth = 4) ----
        f32x4 Chh[2] = { Wyr[0], Wyr[1] };
        f32x4 Chl[2] = { {0,0,0,0}, {0,0,0,0} };
        f32x4 Clh[2] = { {0,0,0,0}, {0,0,0,0} };
        #pragma unroll
        for (int kt = 0; kt < 4; ++kt) {
            #pragma unroll
            for (int n2 = 0; n2 < 2; ++n2)
                Chh[n2] = __builtin_amdgcn_mfma_f32_16x16x32_bf16(Sh[n2][kt], Bh[kt], Chh[n2], 0, 0, 0);
            #pragma unroll
            for (int n2 = 0; n2 < 2; ++n2)
                Chl[n2] = __builtin_amdgcn_mfma_f32_16x16x32_bf16(Sh[n2][kt], Bl[kt], Chl[n2], 0, 0, 0);
            #pragma unroll
            for (int n2 = 0; n2 < 2; ++n2)
                Clh[n2] = __builtin_amdgcn_mfma_f32_16x16x32_bf16(Sl[n2][kt], Bh[kt], Clh[n2], 0, 0, 0);
        }

        // ---- epilogue: sum chains, med3-softthr, cvt_pk split, b64 writes ----
        #pragma unroll
        for (int n2 = 0; n2 < 2; ++n2) {
            float r0, r1, r2, r3;
            {
                const float s0 = Chh[n2][0] + Chl[n2][0] + Clh[n2][0];
                const float s1 = Chh[n2][1] + Chl[n2][1] + Clh[n2][1];
                const float s2 = Chh[n2][2] + Chl[n2][2] + Clh[n2][2];
                const float s3 = Chh[n2][3] + Chl[n2][3] + Clh[n2][3];
                r0 = s0 - med3f(s0, nth, th);
                r1 = s1 - med3f(s1, nth, th);
                r2 = s2 - med3f(s2, nth, th);
                r3 = s3 - med3f(s3, nth, th);
            }
            const unsigned h01 = cvt_pk_bf16(r0, r1);
            const unsigned h23 = cvt_pk_bf16(r2, r3);
            const float l0 = r0 - __uint_as_float(h01 << 16);
            const float l1 = r1 - __uint_as_float(h01 & 0xFFFF0000u);
            const float l2 = r2 - __uint_as_float(h23 << 16);
            const float l3 = r3 - __uint_as_float(h23 & 0xFFFF0000u);
            const unsigned lo01 = cvt_pk_bf16(l0, l1);
            const unsigned lo23 = cvt_pk_bf16(l2, l3);
            *(uint2*)(wh + woff[n2]) = make_uint2(h01, h23);
            *(uint2*)(wl + woff[n2]) = make_uint2(lo01, lo23);
        }

        __syncthreads();          // single barrier: next iter reads what we wrote
        cur ^= 1;
    }

    // ---- output: hi+lo recombine, write global ----
    for (int idx = t; idx < ROWS * N_DIM; idx += NTHREADS) {
        const int r = idx / N_DIM;
        const int j = idx - r * N_DIM;
        const unsigned off = ((unsigned)(r * 256 + j * 2)) ^ ((unsigned)((r & 7) << 4));
        const float v = bf2f(*(const unsigned short*)((const char*)dh[cur] + off))
                      + bf2f(*(const unsigned short*)((const char*)dl[cur] + off));
        out[(size_t)(row0 + r) * N_DIM + j] = v;
    }
}

extern "C" void kernel_launch(void* const* d_in, const int* in_sizes, int n_in,
                              void* d_out, int out_size, void* d_ws, size_t ws_size,
                              hipStream_t stream) {
    const float* y       = (const float*)d_in[0];
    const float* S       = (const float*)d_in[1];
    const float* W       = (const float*)d_in[2];
    const float* thr     = (const float*)d_in[3];
    const int*   numIter = (const int*)d_in[4];
    float* out = (float*)d_out;

    const int Brows = in_sizes[0] / M_DIM;   // 4096
    const int nblk  = Brows / ROWS;          // 256 blocks = 1/CU
    ista_mfma5<<<nblk, NTHREADS, 0, stream>>>(y, S, W, thr, numIter, out);
}